// Round 7
// baseline (3560.218 us; speedup 1.0000x reference)
//
#include <hip/hip_runtime.h>
#include <stdint.h>

#define T_STEPS 599   // T-1 scan steps (x[1:])
#define T_RAW   600
#define NIN     16384
#define N0      4096
#define N1      1024
#define S0W     24    // padded words per S0 row: [pad0][19 spike words][4 zero]

typedef double d4 __attribute__((ext_vector_type(4)));

// ---- workspace layout (bytes) ----
static const size_t OFF_I0T = 0;
static const size_t SZ_I0T  = (size_t)T_STEPS * N0 * 4;      // 9,814,016
static const size_t OFF_S0B = OFF_I0T + SZ_I0T;
static const size_t SZ_S0B  = (size_t)N0 * S0W * 4;          // 393,216
static const size_t OFF_I1  = OFF_S0B + SZ_S0B;
static const size_t SZ_I1   = (size_t)N1 * T_RAW * 4;        // 2,457,600
static const size_t OFF_S1B = OFF_I1 + SZ_I1;                // total ~12.2 MiB

// ============ Kernel 1: I0 = W0 @ X, fp64 MFMA, split-K across waves ============
// Tile 32(M) x 64(N), BK=32, dbuf. Each wave computes the FULL 32x64 tile for
// its k-quarter (k = 8*wid + 0..7): per k-step 6 LDS reads -> 8 MFMAs with 8
// independent acc chains. End: 4-round LDS reduction (Cred aliases staging).
// Pipeline per chunk (proven R5): ds_write -> barrier (vmcnt already 0) ->
// issue next loads -> MFMA. XCD-chunked swizzle (R6). No lambdas/reg arrays.
__global__ __launch_bounds__(256, 5) void gemm_i0_mfma(const float* __restrict__ W0,
                                                       const float* __restrict__ stim,
                                                       float* __restrict__ I0T) {
    __shared__ __align__(16) char smem[27648];
    float* As0 = (float*)(smem);            // 32*36*4 = 4608
    float* As1 = (float*)(smem + 4608);
    float* Bs0 = (float*)(smem + 9216);     // 32*72*4 = 9216
    float* Bs1 = (float*)(smem + 18432);
    const int tid  = threadIdx.x;
    const int lane = tid & 63;
    const int wid  = tid >> 6;
    // XCD-chunked bijective swizzle (1280 % 8 == 0)
    const int flat = blockIdx.x;
    const int idx  = (flat & 7) * 160 + (flat >> 3);
    const int n0   = (idx / 10) * 32;
    const int tau0 = (idx % 10) * 64;
    const int r15  = lane & 15;
    const int c    = lane >> 4;             // k-phase 0..3

    // ---- probe the C/D layout of v_mfma_f64_16x16x4f64 (proven R3) ----
    d4 zero = {0.0, 0.0, 0.0, 0.0};
    const double ap1 = (c == 0) ? 1.0 : 0.0;
    const double bp1 = (c == 0) ? (double)r15 : 0.0;
    d4 pcol = __builtin_amdgcn_mfma_f64_16x16x4f64(ap1, bp1, zero, 0, 0, 0);
    const double ap2 = (c == 0) ? (double)r15 : 0.0;
    const double bp2 = (c == 0) ? 1.0 : 0.0;
    d4 prow = __builtin_amdgcn_mfma_f64_16x16x4f64(ap2, bp2, zero, 0, 0, 0);
    int rowr[4], colr[4];
#pragma unroll
    for (int r = 0; r < 4; ++r) {
        int cc = (int)pcol[r]; cc = cc < 0 ? 0 : (cc > 15 ? 15 : cc);
        int rw = (int)prow[r]; rw = rw < 0 ? 0 : (rw > 15 ? 15 : rw);
        colr[r] = cc; rowr[r] = rw;
    }

    // ---- staging thread mapping (as R5/R6, B pad 72) ----
    const int ar  = tid >> 3;           // A row 0..31
    const int ac4 = (tid & 7) * 4;      // A k-col
    const int br  = tid >> 4;           // B k-row 0..15 (and +16)
    const int bc4 = (tid & 15) * 4;     // B tau-col
    const int t0g = tau0 + bc4;
    const bool fastB = (tau0 + 68) <= T_RAW;

    const float* aP  = W0 + (size_t)(n0 + ar) * NIN + ac4;
    const float* bP0 = stim + (size_t)br * T_RAW + t0g;
    const float* bP1 = stim + (size_t)(br + 16) * T_RAW + t0g;

    float4 aR, bRa, bRb;                // named staging regs (NO arrays)

    // ---- prologue: load chunk 0 ----
    aR = *reinterpret_cast<const float4*>(aP);
    if (fastB) {
        float4 f0 = *reinterpret_cast<const float4*>(bP0);
        float  e0 = bP0[4];
        bRa.x = f0.y; bRa.y = f0.z; bRa.z = f0.w; bRa.w = e0;
        float4 f1 = *reinterpret_cast<const float4*>(bP1);
        float  e1 = bP1[4];
        bRb.x = f1.y; bRb.y = f1.z; bRb.z = f1.w; bRb.w = e1;
    } else {
        bRa.x = (t0g + 0 < T_STEPS) ? bP0[1] : 0.0f;
        bRa.y = (t0g + 1 < T_STEPS) ? bP0[2] : 0.0f;
        bRa.z = (t0g + 2 < T_STEPS) ? bP0[3] : 0.0f;
        bRa.w = (t0g + 3 < T_STEPS) ? bP0[4] : 0.0f;
        bRb.x = (t0g + 0 < T_STEPS) ? bP1[1] : 0.0f;
        bRb.y = (t0g + 1 < T_STEPS) ? bP1[2] : 0.0f;
        bRb.z = (t0g + 2 < T_STEPS) ? bP1[3] : 0.0f;
        bRb.w = (t0g + 3 < T_STEPS) ? bP1[4] : 0.0f;
    }
    aP += 32; bP0 += 32 * T_RAW; bP1 += 32 * T_RAW;

    // 8 named accumulators: c{p}{m}: rows p*16+, cols m*16+
    d4 c00 = {0,0,0,0}, c01 = {0,0,0,0}, c02 = {0,0,0,0}, c03 = {0,0,0,0};
    d4 c10 = {0,0,0,0}, c11 = {0,0,0,0}, c12 = {0,0,0,0}, c13 = {0,0,0,0};

#define STAGE_WRITE(AS, BS)                                               \
    *reinterpret_cast<float4*>(&AS[ar * 36 + ac4]) = aR;                  \
    *reinterpret_cast<float4*>(&BS[br * 72 + bc4]) = bRa;                 \
    *reinterpret_cast<float4*>(&BS[(br + 16) * 72 + bc4]) = bRb;

#define LOAD_NEXT()                                                       \
    aR = *reinterpret_cast<const float4*>(aP);                            \
    if (fastB) {                                                          \
        float4 f0 = *reinterpret_cast<const float4*>(bP0);                \
        float  e0 = bP0[4];                                               \
        bRa.x = f0.y; bRa.y = f0.z; bRa.z = f0.w; bRa.w = e0;             \
        float4 f1 = *reinterpret_cast<const float4*>(bP1);                \
        float  e1 = bP1[4];                                               \
        bRb.x = f1.y; bRb.y = f1.z; bRb.z = f1.w; bRb.w = e1;             \
    } else {                                                              \
        bRa.x = (t0g + 0 < T_STEPS) ? bP0[1] : 0.0f;                      \
        bRa.y = (t0g + 1 < T_STEPS) ? bP0[2] : 0.0f;                      \
        bRa.z = (t0g + 2 < T_STEPS) ? bP0[3] : 0.0f;                      \
        bRa.w = (t0g + 3 < T_STEPS) ? bP0[4] : 0.0f;                      \
        bRb.x = (t0g + 0 < T_STEPS) ? bP1[1] : 0.0f;                      \
        bRb.y = (t0g + 1 < T_STEPS) ? bP1[2] : 0.0f;                      \
        bRb.z = (t0g + 2 < T_STEPS) ? bP1[3] : 0.0f;                      \
        bRb.w = (t0g + 3 < T_STEPS) ? bP1[4] : 0.0f;                      \
    }                                                                     \
    aP += 32; bP0 += 32 * T_RAW; bP1 += 32 * T_RAW;

#define KSTEP(AS, BS, KK)                                                 \
    {                                                                     \
        const double a0 = (double)AS[r15 * 36 + (KK)];                    \
        const double a1 = (double)AS[(16 + r15) * 36 + (KK)];             \
        const double b0 = (double)BS[(KK) * 72 + r15];                    \
        const double b1 = (double)BS[(KK) * 72 + 16 + r15];               \
        const double b2 = (double)BS[(KK) * 72 + 32 + r15];               \
        const double b3 = (double)BS[(KK) * 72 + 48 + r15];               \
        c00 = __builtin_amdgcn_mfma_f64_16x16x4f64(a0, b0, c00, 0, 0, 0); \
        c01 = __builtin_amdgcn_mfma_f64_16x16x4f64(a0, b1, c01, 0, 0, 0); \
        c02 = __builtin_amdgcn_mfma_f64_16x16x4f64(a0, b2, c02, 0, 0, 0); \
        c03 = __builtin_amdgcn_mfma_f64_16x16x4f64(a0, b3, c03, 0, 0, 0); \
        c10 = __builtin_amdgcn_mfma_f64_16x16x4f64(a1, b0, c10, 0, 0, 0); \
        c11 = __builtin_amdgcn_mfma_f64_16x16x4f64(a1, b1, c11, 0, 0, 0); \
        c12 = __builtin_amdgcn_mfma_f64_16x16x4f64(a1, b2, c12, 0, 0, 0); \
        c13 = __builtin_amdgcn_mfma_f64_16x16x4f64(a1, b3, c13, 0, 0, 0); \
    }

#define MFMA_PHASE(AS, BS)                                                \
    __builtin_amdgcn_s_setprio(1);                                        \
    KSTEP(AS, BS, 8 * wid + c);                                           \
    KSTEP(AS, BS, 8 * wid + 4 + c);                                       \
    __builtin_amdgcn_s_setprio(0);

    for (int chp = 0; chp < 256; ++chp) {
        STAGE_WRITE(As0, Bs0);
        __syncthreads();
        LOAD_NEXT();
        MFMA_PHASE(As0, Bs0);
        STAGE_WRITE(As1, Bs1);
        __syncthreads();
        if (chp + 1 < 256) { LOAD_NEXT(); }
        MFMA_PHASE(As1, Bs1);
    }
#undef STAGE_WRITE
#undef LOAD_NEXT
#undef KSTEP
#undef MFMA_PHASE

    // ---- cross-wave reduction: Cred[col][row] aliases the staging LDS ----
    __syncthreads();                      // all LDS traffic of k-loop done
    double* Cred = (double*)smem;         // 64*32*8 = 16384 <= 27648

#define CRED_OP(OP)                                                       \
    _Pragma("unroll")                                                     \
    for (int r = 0; r < 4; ++r) {                                         \
        const int ro = rowr[r], co = colr[r];                             \
        Cred[(co     ) * 32 + ro     ] OP c00[r];                         \
        Cred[(co + 16) * 32 + ro     ] OP c01[r];                         \
        Cred[(co + 32) * 32 + ro     ] OP c02[r];                         \
        Cred[(co + 48) * 32 + ro     ] OP c03[r];                         \
        Cred[(co     ) * 32 + ro + 16] OP c10[r];                         \
        Cred[(co + 16) * 32 + ro + 16] OP c11[r];                         \
        Cred[(co + 32) * 32 + ro + 16] OP c12[r];                         \
        Cred[(co + 48) * 32 + ro + 16] OP c13[r];                         \
    }

    if (wid == 0) { CRED_OP(=) }
    __syncthreads();
    if (wid == 1) { CRED_OP(+=) }
    __syncthreads();
    if (wid == 2) { CRED_OP(+=) }
    __syncthreads();
    if (wid == 3) { CRED_OP(+=) }
    __syncthreads();
#undef CRED_OP

    // ---- store: thread -> (tau col, 8-row strip), float4 x2 ----
    const int scol = tid >> 2;            // 0..63
    const int srow = (tid & 3) * 8;       // 0,8,16,24
    const int tcol = tau0 + scol;
    if (tcol < T_STEPS) {
        const double* cp = &Cred[scol * 32 + srow];
        float4 o0, o1;
        o0.x = (float)cp[0]; o0.y = (float)cp[1]; o0.z = (float)cp[2]; o0.w = (float)cp[3];
        o1.x = (float)cp[4]; o1.y = (float)cp[5]; o1.z = (float)cp[6]; o1.w = (float)cp[7];
        float* op = &I0T[(size_t)tcol * N0 + n0 + srow];
        *reinterpret_cast<float4*>(op)     = o0;
        *reinterpret_cast<float4*>(op + 4) = o1;
    }
}

// ====== Kernel 2: layer-0 LIF scan -> padded bitpacked S0 (unrolled x8) ======
__global__ void lif0(const float* __restrict__ I0T, uint32_t* __restrict__ S0P) {
#pragma clang fp contract(off)
    const int n = blockIdx.x * 256 + threadIdx.x;   // 0..4095
    uint32_t* rowp = S0P + n * S0W;
    rowp[0] = 0u;
    rowp[20] = 0u; rowp[21] = 0u; rowp[22] = 0u; rowp[23] = 0u;
    float v = 0.0f;
    uint32_t word = 0;
    int t = 0;
    for (; t + 8 <= T_STEPS; t += 8) {
        float I[8];
#pragma unroll
        for (int u = 0; u < 8; ++u) I[u] = I0T[(size_t)(t + u) * N0 + n];
#pragma unroll
        for (int u = 0; u < 8; ++u) {
            const int tt = t + u;
            float a = v * 0.9f;        // separate rounding (match jnp)
            v = a + I[u];
            if (v >= 1.0f) { word |= (1u << (tt & 31)); v = 0.0f; }
            if ((tt & 31) == 31) { rowp[1 + (tt >> 5)] = word; word = 0; }
        }
    }
    for (; t < T_STEPS; ++t) {
        float I = I0T[(size_t)t * N0 + n];
        float a = v * 0.9f;
        v = a + I;
        if (v >= 1.0f) { word |= (1u << (t & 31)); v = 0.0f; }
        if ((t & 31) == 31) { rowp[1 + (t >> 5)] = word; word = 0; }
    }
    rowp[1 + (T_STEPS >> 5)] = word;   // word 18 (bits 576..598)
}

// ====== Kernel 3: I1[j][t] = sum_i W1[j,i]*S0[i, t-d(j,i)] ======
__global__ __launch_bounds__(128) void gather_i1(const float* __restrict__ W1,
                                                 const int* __restrict__ delays,
                                                 const uint32_t* __restrict__ S0P,
                                                 float* __restrict__ I1) {
    __shared__ double  wl[N0];   // 32 KB
    __shared__ uint8_t dl[N0];   // 4 KB
    const int j   = blockIdx.x;
    const int tid = threadIdx.x;
    for (int q = tid; q < N0 / 4; q += 128) {
        const float4 w4 = *reinterpret_cast<const float4*>(&W1[(size_t)j * N0 + 4 * q]);
        wl[4 * q + 0] = (double)w4.x; wl[4 * q + 1] = (double)w4.y;
        wl[4 * q + 2] = (double)w4.z; wl[4 * q + 3] = (double)w4.w;
        const int4 dv = *reinterpret_cast<const int4*>(&delays[(size_t)j * N0 + 4 * q]);
        dl[4 * q + 0] = (uint8_t)dv.x; dl[4 * q + 1] = (uint8_t)dv.y;
        dl[4 * q + 2] = (uint8_t)dv.z; dl[4 * q + 3] = (uint8_t)dv.w;
    }
    __syncthreads();
    const int t0 = tid;                         // 0..127
    const bool has4 = (t0 + 512) < T_STEPS;     // t0 < 87
    double a0 = 0.0, a1 = 0.0, a2 = 0.0, a3 = 0.0, a4 = 0.0;
    const uint32_t* rp0 = S0P;
#pragma unroll 2
    for (int i = 0; i < N0; ++i) {
        const int s   = t0 - (int)dl[i];        // in [-15, 127]
        const double w = wl[i];
        const int idx = (s >> 5) + 1;           // 0..4
        const int bit = s & 31;
        const uint32_t r0 = rp0[idx];
        const uint32_t r1 = rp0[idx + 4];
        const uint32_t r2 = rp0[idx + 8];
        const uint32_t r3 = rp0[idx + 12];
        const uint32_t r4 = rp0[idx + 16];
        a0 += ((r0 >> bit) & 1u) ? w : 0.0;
        a1 += ((r1 >> bit) & 1u) ? w : 0.0;
        a2 += ((r2 >> bit) & 1u) ? w : 0.0;
        a3 += ((r3 >> bit) & 1u) ? w : 0.0;
        a4 += ((r4 >> bit) & 1u) ? w : 0.0;
        rp0 += S0W;
    }
    float* orow = I1 + (size_t)j * T_RAW + t0;
    orow[0]   = (float)a0;
    orow[128] = (float)a1;
    orow[256] = (float)a2;
    orow[384] = (float)a3;
    if (has4) orow[512] = (float)a4;
}

// ====== Kernel 4: layer-1 LIF scan -> bitpacked S1 (unrolled x8) ======
__global__ void lif1(const float* __restrict__ I1, uint32_t* __restrict__ S1bits) {
#pragma clang fp contract(off)
    const int j = blockIdx.x * 256 + threadIdx.x;   // 0..1023
    float v = 0.0f;
    uint32_t word = 0;
    int t = 0;
    for (; t + 8 <= T_STEPS; t += 8) {
        float I[8];
#pragma unroll
        for (int u = 0; u < 8; ++u) I[u] = I1[(size_t)j * T_RAW + t + u];
#pragma unroll
        for (int u = 0; u < 8; ++u) {
            const int tt = t + u;
            float a = v * 0.9f;
            v = a + I[u];
            if (v >= 1.0f) { word |= (1u << (tt & 31)); v = 0.0f; }
            if ((tt & 31) == 31) { S1bits[j * 20 + (tt >> 5)] = word; word = 0; }
        }
    }
    for (; t < T_STEPS; ++t) {
        float I = I1[(size_t)j * T_RAW + t];
        float a = v * 0.9f;
        v = a + I;
        if (v >= 1.0f) { word |= (1u << (t & 31)); v = 0.0f; }
        if ((t & 31) == 31) { S1bits[j * 20 + (t >> 5)] = word; word = 0; }
    }
    S1bits[j * 20 + (T_STEPS >> 5)] = word;
}

// ====== Kernel 5: expand bits -> fp32 outputs (S0.T, S1.T) ======
__global__ void expand_out(const uint32_t* __restrict__ S0P,
                           const uint32_t* __restrict__ S1bits,
                           float* __restrict__ out) {
    const int t = blockIdx.x * 256 + threadIdx.x;
    if (t >= T_STEPS) return;
    const int row = blockIdx.y;
    if (row < N0) {
        uint32_t b = (S0P[row * S0W + 1 + (t >> 5)] >> (t & 31)) & 1u;
        out[(size_t)row * T_STEPS + t] = (float)b;
    } else {
        const int jj = row - N0;
        uint32_t b = (S1bits[jj * 20 + (t >> 5)] >> (t & 31)) & 1u;
        out[(size_t)N0 * T_STEPS + (size_t)jj * T_STEPS + t] = (float)b;
    }
}

extern "C" void kernel_launch(void* const* d_in, const int* in_sizes, int n_in,
                              void* d_out, int out_size, void* d_ws, size_t ws_size,
                              hipStream_t stream) {
    const float* stim   = (const float*)d_in[0];   // 128*128*600
    const float* W0     = (const float*)d_in[1];   // 4096*16384
    const float* W1     = (const float*)d_in[2];   // 1024*4096
    const int*   delays = (const int*)d_in[3];     // 1024*4096

    char* ws = (char*)d_ws;
    float*    I0T  = (float*)(ws + OFF_I0T);
    uint32_t* S0b  = (uint32_t*)(ws + OFF_S0B);
    float*    I1   = (float*)(ws + OFF_I1);
    uint32_t* S1b  = (uint32_t*)(ws + OFF_S1B);
    float*    out  = (float*)d_out;

    hipLaunchKernelGGL(gemm_i0_mfma, dim3(1280),   dim3(256), 0, stream, W0, stim, I0T);
    hipLaunchKernelGGL(lif0,         dim3(16),     dim3(256), 0, stream, I0T, S0b);
    hipLaunchKernelGGL(gather_i1,    dim3(1024),   dim3(128), 0, stream, W1, delays, S0b, I1);
    hipLaunchKernelGGL(lif1,         dim3(4),      dim3(256), 0, stream, I1, S1b);
    hipLaunchKernelGGL(expand_out,   dim3(3, N0 + N1), dim3(256), 0, stream, S0b, S1b, out);
}

// Round 8
// 2352.368 us; speedup vs baseline: 1.5135x; 1.5135x over previous
//
#include <hip/hip_runtime.h>
#include <stdint.h>

#define T_STEPS 599   // T-1 scan steps (x[1:])
#define T_RAW   600
#define NIN     16384
#define N0      4096
#define N1      1024
#define S0W     24    // padded words per S0 row: [pad0][19 spike words][4 zero]

typedef double d4 __attribute__((ext_vector_type(4)));

// ---- workspace layout (bytes) ----
static const size_t OFF_I0T = 0;
static const size_t SZ_I0T  = (size_t)T_STEPS * N0 * 4;      // 9,814,016
static const size_t OFF_S0B = OFF_I0T + SZ_I0T;
static const size_t SZ_S0B  = (size_t)N0 * S0W * 4;          // 393,216
static const size_t OFF_I1  = OFF_S0B + SZ_S0B;
static const size_t SZ_I1   = (size_t)N1 * T_RAW * 4;        // 2,457,600
static const size_t OFF_S1B = OFF_I1 + SZ_I1;                // total ~12.2 MiB

// ========== Kernel 1: I0 = W0 @ X, fp64 MFMA, 2x2 wave split (K half x N half) ==========
// Tile 32(M) x 64(N), BK=32, dbuf. Wave (kh,nh)=(wid>>1,wid&1) computes the
// 32x32 quarter (tau cols nh*32..+32) for k in [16*kh,16*kh+16): per k-step
// 4 LDS reads -> 4 MFMAs, 4 independent acc chains, acc = 4 x d4 = 32 VGPR
// (fits launch_bounds(256,5) budget ~96; R7's 8-acc variant spilled).
// End: 2-round LDS reduction over kh. Pipeline per chunk (proven R5):
// ds_write -> barrier (vmcnt already 0) -> issue next loads -> MFMA.
// XCD-chunked swizzle (R6). No lambdas / no register arrays (R4 lesson).
__global__ __launch_bounds__(256, 5) void gemm_i0_mfma(const float* __restrict__ W0,
                                                       const float* __restrict__ stim,
                                                       float* __restrict__ I0T) {
    __shared__ __align__(16) char smem[27648];
    float* As0 = (float*)(smem);            // 32*36*4 = 4608
    float* As1 = (float*)(smem + 4608);
    float* Bs0 = (float*)(smem + 9216);     // 32*72*4 = 9216
    float* Bs1 = (float*)(smem + 18432);
    const int tid  = threadIdx.x;
    const int lane = tid & 63;
    const int wid  = tid >> 6;
    const int kbase = 16 * (wid >> 1);      // k half: 0 or 16
    const int coff  = 32 * (wid & 1);       // tau half: 0 or 32
    // XCD-chunked bijective swizzle (1280 % 8 == 0)
    const int flat = blockIdx.x;
    const int idx  = (flat & 7) * 160 + (flat >> 3);
    const int n0   = (idx / 10) * 32;
    const int tau0 = (idx % 10) * 64;
    const int r15  = lane & 15;
    const int c    = lane >> 4;             // k-phase 0..3

    // ---- probe the C/D layout of v_mfma_f64_16x16x4f64 (proven R3) ----
    d4 zero = {0.0, 0.0, 0.0, 0.0};
    const double ap1 = (c == 0) ? 1.0 : 0.0;
    const double bp1 = (c == 0) ? (double)r15 : 0.0;
    d4 pcol = __builtin_amdgcn_mfma_f64_16x16x4f64(ap1, bp1, zero, 0, 0, 0);
    const double ap2 = (c == 0) ? (double)r15 : 0.0;
    const double bp2 = (c == 0) ? 1.0 : 0.0;
    d4 prow = __builtin_amdgcn_mfma_f64_16x16x4f64(ap2, bp2, zero, 0, 0, 0);
    int rowr[4], colr[4];
#pragma unroll
    for (int r = 0; r < 4; ++r) {
        int cc = (int)pcol[r]; cc = cc < 0 ? 0 : (cc > 15 ? 15 : cc);
        int rw = (int)prow[r]; rw = rw < 0 ? 0 : (rw > 15 ? 15 : rw);
        colr[r] = cc; rowr[r] = rw;
    }

    // ---- staging thread mapping (as R5/R6, B pad 72) ----
    const int ar  = tid >> 3;           // A row 0..31
    const int ac4 = (tid & 7) * 4;      // A k-col
    const int br  = tid >> 4;           // B k-row 0..15 (and +16)
    const int bc4 = (tid & 15) * 4;     // B tau-col
    const int t0g = tau0 + bc4;
    const bool fastB = (tau0 + 68) <= T_RAW;

    const float* aP  = W0 + (size_t)(n0 + ar) * NIN + ac4;
    const float* bP0 = stim + (size_t)br * T_RAW + t0g;
    const float* bP1 = stim + (size_t)(br + 16) * T_RAW + t0g;

    float4 aR, bRa, bRb;                // named staging regs (NO arrays)

    // ---- prologue: load chunk 0 ----
    aR = *reinterpret_cast<const float4*>(aP);
    if (fastB) {
        float4 f0 = *reinterpret_cast<const float4*>(bP0);
        float  e0 = bP0[4];
        bRa.x = f0.y; bRa.y = f0.z; bRa.z = f0.w; bRa.w = e0;
        float4 f1 = *reinterpret_cast<const float4*>(bP1);
        float  e1 = bP1[4];
        bRb.x = f1.y; bRb.y = f1.z; bRb.z = f1.w; bRb.w = e1;
    } else {
        bRa.x = (t0g + 0 < T_STEPS) ? bP0[1] : 0.0f;
        bRa.y = (t0g + 1 < T_STEPS) ? bP0[2] : 0.0f;
        bRa.z = (t0g + 2 < T_STEPS) ? bP0[3] : 0.0f;
        bRa.w = (t0g + 3 < T_STEPS) ? bP0[4] : 0.0f;
        bRb.x = (t0g + 0 < T_STEPS) ? bP1[1] : 0.0f;
        bRb.y = (t0g + 1 < T_STEPS) ? bP1[2] : 0.0f;
        bRb.z = (t0g + 2 < T_STEPS) ? bP1[3] : 0.0f;
        bRb.w = (t0g + 3 < T_STEPS) ? bP1[4] : 0.0f;
    }
    aP += 32; bP0 += 32 * T_RAW; bP1 += 32 * T_RAW;

    // 4 named accumulators: c{p}{m}: rows p*16+, cols coff + m*16+
    d4 c00 = {0,0,0,0}, c01 = {0,0,0,0};
    d4 c10 = {0,0,0,0}, c11 = {0,0,0,0};

#define STAGE_WRITE(AS, BS)                                               \
    *reinterpret_cast<float4*>(&AS[ar * 36 + ac4]) = aR;                  \
    *reinterpret_cast<float4*>(&BS[br * 72 + bc4]) = bRa;                 \
    *reinterpret_cast<float4*>(&BS[(br + 16) * 72 + bc4]) = bRb;

#define LOAD_NEXT()                                                       \
    aR = *reinterpret_cast<const float4*>(aP);                            \
    if (fastB) {                                                          \
        float4 f0 = *reinterpret_cast<const float4*>(bP0);                \
        float  e0 = bP0[4];                                               \
        bRa.x = f0.y; bRa.y = f0.z; bRa.z = f0.w; bRa.w = e0;             \
        float4 f1 = *reinterpret_cast<const float4*>(bP1);                \
        float  e1 = bP1[4];                                               \
        bRb.x = f1.y; bRb.y = f1.z; bRb.z = f1.w; bRb.w = e1;             \
    } else {                                                              \
        bRa.x = (t0g + 0 < T_STEPS) ? bP0[1] : 0.0f;                      \
        bRa.y = (t0g + 1 < T_STEPS) ? bP0[2] : 0.0f;                      \
        bRa.z = (t0g + 2 < T_STEPS) ? bP0[3] : 0.0f;                      \
        bRa.w = (t0g + 3 < T_STEPS) ? bP0[4] : 0.0f;                      \
        bRb.x = (t0g + 0 < T_STEPS) ? bP1[1] : 0.0f;                      \
        bRb.y = (t0g + 1 < T_STEPS) ? bP1[2] : 0.0f;                      \
        bRb.z = (t0g + 2 < T_STEPS) ? bP1[3] : 0.0f;                      \
        bRb.w = (t0g + 3 < T_STEPS) ? bP1[4] : 0.0f;                      \
    }                                                                     \
    aP += 32; bP0 += 32 * T_RAW; bP1 += 32 * T_RAW;

#define KSTEP(AS, BS, KK)                                                 \
    {                                                                     \
        const double a0 = (double)AS[r15 * 36 + (KK)];                    \
        const double a1 = (double)AS[(16 + r15) * 36 + (KK)];             \
        const double b0 = (double)BS[(KK) * 72 + coff + r15];             \
        const double b1 = (double)BS[(KK) * 72 + coff + 16 + r15];        \
        c00 = __builtin_amdgcn_mfma_f64_16x16x4f64(a0, b0, c00, 0, 0, 0); \
        c01 = __builtin_amdgcn_mfma_f64_16x16x4f64(a0, b1, c01, 0, 0, 0); \
        c10 = __builtin_amdgcn_mfma_f64_16x16x4f64(a1, b0, c10, 0, 0, 0); \
        c11 = __builtin_amdgcn_mfma_f64_16x16x4f64(a1, b1, c11, 0, 0, 0); \
    }

#define MFMA_PHASE(AS, BS)                                                \
    __builtin_amdgcn_s_setprio(1);                                        \
    KSTEP(AS, BS, kbase + c);                                             \
    KSTEP(AS, BS, kbase + 4 + c);                                         \
    KSTEP(AS, BS, kbase + 8 + c);                                         \
    KSTEP(AS, BS, kbase + 12 + c);                                        \
    __builtin_amdgcn_s_setprio(0);

    for (int chp = 0; chp < 256; ++chp) {
        STAGE_WRITE(As0, Bs0);
        __syncthreads();
        LOAD_NEXT();
        MFMA_PHASE(As0, Bs0);
        STAGE_WRITE(As1, Bs1);
        __syncthreads();
        if (chp + 1 < 256) { LOAD_NEXT(); }
        MFMA_PHASE(As1, Bs1);
    }
#undef STAGE_WRITE
#undef LOAD_NEXT
#undef KSTEP
#undef MFMA_PHASE

    // ---- cross-wave reduction over kh: Cred[col][row] aliases staging LDS ----
    __syncthreads();                      // all LDS traffic of k-loop done
    double* Cred = (double*)smem;         // 64*32*8 = 16384 <= 27648

#define CRED_OP(OP)                                                       \
    _Pragma("unroll")                                                     \
    for (int r = 0; r < 4; ++r) {                                         \
        const int ro = rowr[r], co = coff + colr[r];                      \
        Cred[(co     ) * 32 + ro     ] OP c00[r];                         \
        Cred[(co + 16) * 32 + ro     ] OP c01[r];                         \
        Cred[(co     ) * 32 + ro + 16] OP c10[r];                         \
        Cred[(co + 16) * 32 + ro + 16] OP c11[r];                         \
    }

    if (wid < 2)  { CRED_OP(=) }          // kh=0: waves 0,1 (disjoint cols)
    __syncthreads();
    if (wid >= 2) { CRED_OP(+=) }         // kh=1: waves 2,3 add
    __syncthreads();
#undef CRED_OP

    // ---- store: thread -> (tau col, 8-row strip), float4 x2 ----
    const int scol = tid >> 2;            // 0..63
    const int srow = (tid & 3) * 8;       // 0,8,16,24
    const int tcol = tau0 + scol;
    if (tcol < T_STEPS) {
        const double* cp = &Cred[scol * 32 + srow];
        float4 o0, o1;
        o0.x = (float)cp[0]; o0.y = (float)cp[1]; o0.z = (float)cp[2]; o0.w = (float)cp[3];
        o1.x = (float)cp[4]; o1.y = (float)cp[5]; o1.z = (float)cp[6]; o1.w = (float)cp[7];
        float* op = &I0T[(size_t)tcol * N0 + n0 + srow];
        *reinterpret_cast<float4*>(op)     = o0;
        *reinterpret_cast<float4*>(op + 4) = o1;
    }
}

// ====== Kernel 2: layer-0 LIF scan -> padded bitpacked S0 (unrolled x8) ======
__global__ void lif0(const float* __restrict__ I0T, uint32_t* __restrict__ S0P) {
#pragma clang fp contract(off)
    const int n = blockIdx.x * 256 + threadIdx.x;   // 0..4095
    uint32_t* rowp = S0P + n * S0W;
    rowp[0] = 0u;
    rowp[20] = 0u; rowp[21] = 0u; rowp[22] = 0u; rowp[23] = 0u;
    float v = 0.0f;
    uint32_t word = 0;
    int t = 0;
    for (; t + 8 <= T_STEPS; t += 8) {
        float I[8];
#pragma unroll
        for (int u = 0; u < 8; ++u) I[u] = I0T[(size_t)(t + u) * N0 + n];
#pragma unroll
        for (int u = 0; u < 8; ++u) {
            const int tt = t + u;
            float a = v * 0.9f;        // separate rounding (match jnp)
            v = a + I[u];
            if (v >= 1.0f) { word |= (1u << (tt & 31)); v = 0.0f; }
            if ((tt & 31) == 31) { rowp[1 + (tt >> 5)] = word; word = 0; }
        }
    }
    for (; t < T_STEPS; ++t) {
        float I = I0T[(size_t)t * N0 + n];
        float a = v * 0.9f;
        v = a + I;
        if (v >= 1.0f) { word |= (1u << (t & 31)); v = 0.0f; }
        if ((t & 31) == 31) { rowp[1 + (t >> 5)] = word; word = 0; }
    }
    rowp[1 + (T_STEPS >> 5)] = word;   // word 18 (bits 576..598)
}

// ====== Kernel 3: I1[j][t] = sum_i W1[j,i]*S0[i, t-d(j,i)] ======
__global__ __launch_bounds__(128) void gather_i1(const float* __restrict__ W1,
                                                 const int* __restrict__ delays,
                                                 const uint32_t* __restrict__ S0P,
                                                 float* __restrict__ I1) {
    __shared__ double  wl[N0];   // 32 KB
    __shared__ uint8_t dl[N0];   // 4 KB
    const int j   = blockIdx.x;
    const int tid = threadIdx.x;
    for (int q = tid; q < N0 / 4; q += 128) {
        const float4 w4 = *reinterpret_cast<const float4*>(&W1[(size_t)j * N0 + 4 * q]);
        wl[4 * q + 0] = (double)w4.x; wl[4 * q + 1] = (double)w4.y;
        wl[4 * q + 2] = (double)w4.z; wl[4 * q + 3] = (double)w4.w;
        const int4 dv = *reinterpret_cast<const int4*>(&delays[(size_t)j * N0 + 4 * q]);
        dl[4 * q + 0] = (uint8_t)dv.x; dl[4 * q + 1] = (uint8_t)dv.y;
        dl[4 * q + 2] = (uint8_t)dv.z; dl[4 * q + 3] = (uint8_t)dv.w;
    }
    __syncthreads();
    const int t0 = tid;                         // 0..127
    const bool has4 = (t0 + 512) < T_STEPS;     // t0 < 87
    double a0 = 0.0, a1 = 0.0, a2 = 0.0, a3 = 0.0, a4 = 0.0;
    const uint32_t* rp0 = S0P;
#pragma unroll 2
    for (int i = 0; i < N0; ++i) {
        const int s   = t0 - (int)dl[i];        // in [-15, 127]
        const double w = wl[i];
        const int idx = (s >> 5) + 1;           // 0..4
        const int bit = s & 31;
        const uint32_t r0 = rp0[idx];
        const uint32_t r1 = rp0[idx + 4];
        const uint32_t r2 = rp0[idx + 8];
        const uint32_t r3 = rp0[idx + 12];
        const uint32_t r4 = rp0[idx + 16];
        a0 += ((r0 >> bit) & 1u) ? w : 0.0;
        a1 += ((r1 >> bit) & 1u) ? w : 0.0;
        a2 += ((r2 >> bit) & 1u) ? w : 0.0;
        a3 += ((r3 >> bit) & 1u) ? w : 0.0;
        a4 += ((r4 >> bit) & 1u) ? w : 0.0;
        rp0 += S0W;
    }
    float* orow = I1 + (size_t)j * T_RAW + t0;
    orow[0]   = (float)a0;
    orow[128] = (float)a1;
    orow[256] = (float)a2;
    orow[384] = (float)a3;
    if (has4) orow[512] = (float)a4;
}

// ====== Kernel 4: layer-1 LIF scan -> bitpacked S1 (unrolled x8) ======
__global__ void lif1(const float* __restrict__ I1, uint32_t* __restrict__ S1bits) {
#pragma clang fp contract(off)
    const int j = blockIdx.x * 256 + threadIdx.x;   // 0..1023
    float v = 0.0f;
    uint32_t word = 0;
    int t = 0;
    for (; t + 8 <= T_STEPS; t += 8) {
        float I[8];
#pragma unroll
        for (int u = 0; u < 8; ++u) I[u] = I1[(size_t)j * T_RAW + t + u];
#pragma unroll
        for (int u = 0; u < 8; ++u) {
            const int tt = t + u;
            float a = v * 0.9f;
            v = a + I[u];
            if (v >= 1.0f) { word |= (1u << (tt & 31)); v = 0.0f; }
            if ((tt & 31) == 31) { S1bits[j * 20 + (tt >> 5)] = word; word = 0; }
        }
    }
    for (; t < T_STEPS; ++t) {
        float I = I1[(size_t)j * T_RAW + t];
        float a = v * 0.9f;
        v = a + I;
        if (v >= 1.0f) { word |= (1u << (t & 31)); v = 0.0f; }
        if ((t & 31) == 31) { S1bits[j * 20 + (t >> 5)] = word; word = 0; }
    }
    S1bits[j * 20 + (T_STEPS >> 5)] = word;
}

// ====== Kernel 5: expand bits -> fp32 outputs (S0.T, S1.T) ======
__global__ void expand_out(const uint32_t* __restrict__ S0P,
                           const uint32_t* __restrict__ S1bits,
                           float* __restrict__ out) {
    const int t = blockIdx.x * 256 + threadIdx.x;
    if (t >= T_STEPS) return;
    const int row = blockIdx.y;
    if (row < N0) {
        uint32_t b = (S0P[row * S0W + 1 + (t >> 5)] >> (t & 31)) & 1u;
        out[(size_t)row * T_STEPS + t] = (float)b;
    } else {
        const int jj = row - N0;
        uint32_t b = (S1bits[jj * 20 + (t >> 5)] >> (t & 31)) & 1u;
        out[(size_t)N0 * T_STEPS + (size_t)jj * T_STEPS + t] = (float)b;
    }
}

extern "C" void kernel_launch(void* const* d_in, const int* in_sizes, int n_in,
                              void* d_out, int out_size, void* d_ws, size_t ws_size,
                              hipStream_t stream) {
    const float* stim   = (const float*)d_in[0];   // 128*128*600
    const float* W0     = (const float*)d_in[1];   // 4096*16384
    const float* W1     = (const float*)d_in[2];   // 1024*4096
    const int*   delays = (const int*)d_in[3];     // 1024*4096

    char* ws = (char*)d_ws;
    float*    I0T  = (float*)(ws + OFF_I0T);
    uint32_t* S0b  = (uint32_t*)(ws + OFF_S0B);
    float*    I1   = (float*)(ws + OFF_I1);
    uint32_t* S1b  = (uint32_t*)(ws + OFF_S1B);
    float*    out  = (float*)d_out;

    hipLaunchKernelGGL(gemm_i0_mfma, dim3(1280),   dim3(256), 0, stream, W0, stim, I0T);
    hipLaunchKernelGGL(lif0,         dim3(16),     dim3(256), 0, stream, I0T, S0b);
    hipLaunchKernelGGL(gather_i1,    dim3(1024),   dim3(128), 0, stream, W1, delays, S0b, I1);
    hipLaunchKernelGGL(lif1,         dim3(4),      dim3(256), 0, stream, I1, S1b);
    hipLaunchKernelGGL(expand_out,   dim3(3, N0 + N1), dim3(256), 0, stream, S0b, S1b, out);
}

// Round 9
// 2291.477 us; speedup vs baseline: 1.5537x; 1.0266x over previous
//
#include <hip/hip_runtime.h>
#include <stdint.h>
#include <math.h>

#define T_STEPS 599   // T-1 scan steps (x[1:])
#define T_RAW   600
#define NIN     16384
#define N0      4096
#define N1      1024
#define S0W     24    // padded words per S0 row: [pad0][19 spike words][4 zero]

typedef double d4 __attribute__((ext_vector_type(4)));

// ---- workspace layout (bytes) ----
static const size_t OFF_I0T = 0;
static const size_t SZ_I0T  = (size_t)T_STEPS * N0 * 4;      // 9,814,016
static const size_t OFF_S0B = OFF_I0T + SZ_I0T;
static const size_t SZ_S0B  = (size_t)N0 * S0W * 4;          // 393,216
static const size_t OFF_I1  = OFF_S0B + SZ_S0B;
static const size_t SZ_I1   = (size_t)N1 * T_RAW * 4;        // 2,457,600
static const size_t OFF_S1B = OFF_I1 + SZ_I1;                // total ~12.2 MiB

// ========== Kernel 1: I0 = W0 @ X, fp64 MFMA, 2x2 wave split ==========
// As in R8 (1640us, MfmaUtil 73%) with ONE change: A-tile pad 36 -> 37.
// Pad 36: bank = (4*r15+k)%32 -> 64 lanes on 8 banks = 8-way conflict (2.94x).
// Pad 37: bank = (5*r15+k)%32, 5 coprime 32 -> max 2-way (free, m136).
__global__ __launch_bounds__(256, 5) void gemm_i0_mfma(const float* __restrict__ W0,
                                                       const float* __restrict__ stim,
                                                       float* __restrict__ I0T) {
    __shared__ __align__(16) char smem[27904];
    float* As0 = (float*)(smem);            // 32*37*4 = 4736
    float* As1 = (float*)(smem + 4736);
    float* Bs0 = (float*)(smem + 9472);     // 32*72*4 = 9216
    float* Bs1 = (float*)(smem + 18688);
    const int tid  = threadIdx.x;
    const int lane = tid & 63;
    const int wid  = tid >> 6;
    const int kbase = 16 * (wid >> 1);      // k half: 0 or 16
    const int coff  = 32 * (wid & 1);       // tau half: 0 or 32
    // XCD-chunked bijective swizzle (1280 % 8 == 0)
    const int flat = blockIdx.x;
    const int idx  = (flat & 7) * 160 + (flat >> 3);
    const int n0   = (idx / 10) * 32;
    const int tau0 = (idx % 10) * 64;
    const int r15  = lane & 15;
    const int c    = lane >> 4;             // k-phase 0..3

    // ---- probe the C/D layout of v_mfma_f64_16x16x4f64 (proven R3) ----
    d4 zero = {0.0, 0.0, 0.0, 0.0};
    const double ap1 = (c == 0) ? 1.0 : 0.0;
    const double bp1 = (c == 0) ? (double)r15 : 0.0;
    d4 pcol = __builtin_amdgcn_mfma_f64_16x16x4f64(ap1, bp1, zero, 0, 0, 0);
    const double ap2 = (c == 0) ? (double)r15 : 0.0;
    const double bp2 = (c == 0) ? 1.0 : 0.0;
    d4 prow = __builtin_amdgcn_mfma_f64_16x16x4f64(ap2, bp2, zero, 0, 0, 0);
    int rowr[4], colr[4];
#pragma unroll
    for (int r = 0; r < 4; ++r) {
        int cc = (int)pcol[r]; cc = cc < 0 ? 0 : (cc > 15 ? 15 : cc);
        int rw = (int)prow[r]; rw = rw < 0 ? 0 : (rw > 15 ? 15 : rw);
        colr[r] = cc; rowr[r] = rw;
    }

    // ---- staging thread mapping ----
    const int ar  = tid >> 3;           // A row 0..31
    const int ac4 = (tid & 7) * 4;      // A k-col
    const int br  = tid >> 4;           // B k-row 0..15 (and +16)
    const int bc4 = (tid & 15) * 4;     // B tau-col
    const int t0g = tau0 + bc4;
    const bool fastB = (tau0 + 68) <= T_RAW;

    const float* aP  = W0 + (size_t)(n0 + ar) * NIN + ac4;
    const float* bP0 = stim + (size_t)br * T_RAW + t0g;
    const float* bP1 = stim + (size_t)(br + 16) * T_RAW + t0g;

    float4 aR, bRa, bRb;                // named staging regs (NO arrays)

    // ---- prologue: load chunk 0 ----
    aR = *reinterpret_cast<const float4*>(aP);
    if (fastB) {
        float4 f0 = *reinterpret_cast<const float4*>(bP0);
        float  e0 = bP0[4];
        bRa.x = f0.y; bRa.y = f0.z; bRa.z = f0.w; bRa.w = e0;
        float4 f1 = *reinterpret_cast<const float4*>(bP1);
        float  e1 = bP1[4];
        bRb.x = f1.y; bRb.y = f1.z; bRb.z = f1.w; bRb.w = e1;
    } else {
        bRa.x = (t0g + 0 < T_STEPS) ? bP0[1] : 0.0f;
        bRa.y = (t0g + 1 < T_STEPS) ? bP0[2] : 0.0f;
        bRa.z = (t0g + 2 < T_STEPS) ? bP0[3] : 0.0f;
        bRa.w = (t0g + 3 < T_STEPS) ? bP0[4] : 0.0f;
        bRb.x = (t0g + 0 < T_STEPS) ? bP1[1] : 0.0f;
        bRb.y = (t0g + 1 < T_STEPS) ? bP1[2] : 0.0f;
        bRb.z = (t0g + 2 < T_STEPS) ? bP1[3] : 0.0f;
        bRb.w = (t0g + 3 < T_STEPS) ? bP1[4] : 0.0f;
    }
    aP += 32; bP0 += 32 * T_RAW; bP1 += 32 * T_RAW;

    // 4 named accumulators: c{p}{m}: rows p*16+, cols coff + m*16+
    d4 c00 = {0,0,0,0}, c01 = {0,0,0,0};
    d4 c10 = {0,0,0,0}, c11 = {0,0,0,0};

#define STAGE_WRITE(AS, BS)                                               \
    *reinterpret_cast<float4*>(&AS[ar * 37 + ac4]) = aR;                  \
    *reinterpret_cast<float4*>(&BS[br * 72 + bc4]) = bRa;                 \
    *reinterpret_cast<float4*>(&BS[(br + 16) * 72 + bc4]) = bRb;

#define LOAD_NEXT()                                                       \
    aR = *reinterpret_cast<const float4*>(aP);                            \
    if (fastB) {                                                          \
        float4 f0 = *reinterpret_cast<const float4*>(bP0);                \
        float  e0 = bP0[4];                                               \
        bRa.x = f0.y; bRa.y = f0.z; bRa.z = f0.w; bRa.w = e0;             \
        float4 f1 = *reinterpret_cast<const float4*>(bP1);                \
        float  e1 = bP1[4];                                               \
        bRb.x = f1.y; bRb.y = f1.z; bRb.z = f1.w; bRb.w = e1;             \
    } else {                                                              \
        bRa.x = (t0g + 0 < T_STEPS) ? bP0[1] : 0.0f;                      \
        bRa.y = (t0g + 1 < T_STEPS) ? bP0[2] : 0.0f;                      \
        bRa.z = (t0g + 2 < T_STEPS) ? bP0[3] : 0.0f;                      \
        bRa.w = (t0g + 3 < T_STEPS) ? bP0[4] : 0.0f;                      \
        bRb.x = (t0g + 0 < T_STEPS) ? bP1[1] : 0.0f;                      \
        bRb.y = (t0g + 1 < T_STEPS) ? bP1[2] : 0.0f;                      \
        bRb.z = (t0g + 2 < T_STEPS) ? bP1[3] : 0.0f;                      \
        bRb.w = (t0g + 3 < T_STEPS) ? bP1[4] : 0.0f;                      \
    }                                                                     \
    aP += 32; bP0 += 32 * T_RAW; bP1 += 32 * T_RAW;

#define KSTEP(AS, BS, KK)                                                 \
    {                                                                     \
        const double a0 = (double)AS[r15 * 37 + (KK)];                    \
        const double a1 = (double)AS[(16 + r15) * 37 + (KK)];             \
        const double b0 = (double)BS[(KK) * 72 + coff + r15];             \
        const double b1 = (double)BS[(KK) * 72 + coff + 16 + r15];        \
        c00 = __builtin_amdgcn_mfma_f64_16x16x4f64(a0, b0, c00, 0, 0, 0); \
        c01 = __builtin_amdgcn_mfma_f64_16x16x4f64(a0, b1, c01, 0, 0, 0); \
        c10 = __builtin_amdgcn_mfma_f64_16x16x4f64(a1, b0, c10, 0, 0, 0); \
        c11 = __builtin_amdgcn_mfma_f64_16x16x4f64(a1, b1, c11, 0, 0, 0); \
    }

#define MFMA_PHASE(AS, BS)                                                \
    __builtin_amdgcn_s_setprio(1);                                        \
    KSTEP(AS, BS, kbase + c);                                             \
    KSTEP(AS, BS, kbase + 4 + c);                                         \
    KSTEP(AS, BS, kbase + 8 + c);                                         \
    KSTEP(AS, BS, kbase + 12 + c);                                        \
    __builtin_amdgcn_s_setprio(0);

    for (int chp = 0; chp < 256; ++chp) {
        STAGE_WRITE(As0, Bs0);
        __syncthreads();
        LOAD_NEXT();
        MFMA_PHASE(As0, Bs0);
        STAGE_WRITE(As1, Bs1);
        __syncthreads();
        if (chp + 1 < 256) { LOAD_NEXT(); }
        MFMA_PHASE(As1, Bs1);
    }
#undef STAGE_WRITE
#undef LOAD_NEXT
#undef KSTEP
#undef MFMA_PHASE

    // ---- cross-wave reduction over kh: Cred[col][row] aliases staging LDS ----
    __syncthreads();                      // all LDS traffic of k-loop done
    double* Cred = (double*)smem;         // 64*32*8 = 16384 <= 27904

#define CRED_OP(OP)                                                       \
    _Pragma("unroll")                                                     \
    for (int r = 0; r < 4; ++r) {                                         \
        const int ro = rowr[r], co = coff + colr[r];                      \
        Cred[(co     ) * 32 + ro     ] OP c00[r];                         \
        Cred[(co + 16) * 32 + ro     ] OP c01[r];                         \
        Cred[(co     ) * 32 + ro + 16] OP c10[r];                         \
        Cred[(co + 16) * 32 + ro + 16] OP c11[r];                         \
    }

    if (wid < 2)  { CRED_OP(=) }          // kh=0: waves 0,1 (disjoint cols)
    __syncthreads();
    if (wid >= 2) { CRED_OP(+=) }         // kh=1: waves 2,3 add
    __syncthreads();
#undef CRED_OP

    // ---- store: thread -> (tau col, 8-row strip), float4 x2 ----
    const int scol = tid >> 2;            // 0..63
    const int srow = (tid & 3) * 8;       // 0,8,16,24
    const int tcol = tau0 + scol;
    if (tcol < T_STEPS) {
        const double* cp = &Cred[scol * 32 + srow];
        float4 o0, o1;
        o0.x = (float)cp[0]; o0.y = (float)cp[1]; o0.z = (float)cp[2]; o0.w = (float)cp[3];
        o1.x = (float)cp[4]; o1.y = (float)cp[5]; o1.z = (float)cp[6]; o1.w = (float)cp[7];
        float* op = &I0T[(size_t)tcol * N0 + n0 + srow];
        *reinterpret_cast<float4*>(op)     = o0;
        *reinterpret_cast<float4*>(op + 4) = o1;
    }
}

// ====== Kernel 2: layer-0 LIF scan -> padded bitpacked S0 (unrolled x8) ======
__global__ void lif0(const float* __restrict__ I0T, uint32_t* __restrict__ S0P) {
#pragma clang fp contract(off)
    const int n = blockIdx.x * 256 + threadIdx.x;   // 0..4095
    uint32_t* rowp = S0P + n * S0W;
    rowp[0] = 0u;
    rowp[20] = 0u; rowp[21] = 0u; rowp[22] = 0u; rowp[23] = 0u;
    float v = 0.0f;
    uint32_t word = 0;
    int t = 0;
    for (; t + 8 <= T_STEPS; t += 8) {
        float I[8];
#pragma unroll
        for (int u = 0; u < 8; ++u) I[u] = I0T[(size_t)(t + u) * N0 + n];
#pragma unroll
        for (int u = 0; u < 8; ++u) {
            const int tt = t + u;
            float a = v * 0.9f;        // separate rounding (match jnp)
            v = a + I[u];
            if (v >= 1.0f) { word |= (1u << (tt & 31)); v = 0.0f; }
            if ((tt & 31) == 31) { rowp[1 + (tt >> 5)] = word; word = 0; }
        }
    }
    for (; t < T_STEPS; ++t) {
        float I = I0T[(size_t)t * N0 + n];
        float a = v * 0.9f;
        v = a + I;
        if (v >= 1.0f) { word |= (1u << (t & 31)); v = 0.0f; }
        if ((t & 31) == 31) { rowp[1 + (t >> 5)] = word; word = 0; }
    }
    rowp[1 + (T_STEPS >> 5)] = word;   // word 18 (bits 576..598)
}

// ====== Kernel 3: I1[j][t] = sum_i W1[j,i]*S0[i, t-d(j,i)] ======
// fma formulation: a += (double)bit * w  (bit-exact: w*1=w, w*0=0) compiles
// to bfe+cvt+fma = 3 VALU/point vs ~6 for the cndmask select path.
__global__ __launch_bounds__(128) void gather_i1(const float* __restrict__ W1,
                                                 const int* __restrict__ delays,
                                                 const uint32_t* __restrict__ S0P,
                                                 float* __restrict__ I1) {
    __shared__ double  wl[N0];   // 32 KB
    __shared__ uint8_t dl[N0];   // 4 KB
    const int j   = blockIdx.x;
    const int tid = threadIdx.x;
    for (int q = tid; q < N0 / 4; q += 128) {
        const float4 w4 = *reinterpret_cast<const float4*>(&W1[(size_t)j * N0 + 4 * q]);
        wl[4 * q + 0] = (double)w4.x; wl[4 * q + 1] = (double)w4.y;
        wl[4 * q + 2] = (double)w4.z; wl[4 * q + 3] = (double)w4.w;
        const int4 dv = *reinterpret_cast<const int4*>(&delays[(size_t)j * N0 + 4 * q]);
        dl[4 * q + 0] = (uint8_t)dv.x; dl[4 * q + 1] = (uint8_t)dv.y;
        dl[4 * q + 2] = (uint8_t)dv.z; dl[4 * q + 3] = (uint8_t)dv.w;
    }
    __syncthreads();
    const int t0 = tid;                         // 0..127
    const bool has4 = (t0 + 512) < T_STEPS;     // t0 < 87
    double a0 = 0.0, a1 = 0.0, a2 = 0.0, a3 = 0.0, a4 = 0.0;
    const uint32_t* rp0 = S0P;
#pragma unroll 2
    for (int i = 0; i < N0; ++i) {
        const int s   = t0 - (int)dl[i];        // in [-15, 127]
        const double w = wl[i];
        const int idx = (s >> 5) + 1;           // 0..4
        const int bit = s & 31;
        const uint32_t r0 = rp0[idx];
        const uint32_t r1 = rp0[idx + 4];
        const uint32_t r2 = rp0[idx + 8];
        const uint32_t r3 = rp0[idx + 12];
        const uint32_t r4 = rp0[idx + 16];
        a0 = fma((double)((r0 >> bit) & 1u), w, a0);
        a1 = fma((double)((r1 >> bit) & 1u), w, a1);
        a2 = fma((double)((r2 >> bit) & 1u), w, a2);
        a3 = fma((double)((r3 >> bit) & 1u), w, a3);
        a4 = fma((double)((r4 >> bit) & 1u), w, a4);
        rp0 += S0W;
    }
    float* orow = I1 + (size_t)j * T_RAW + t0;
    orow[0]   = (float)a0;
    orow[128] = (float)a1;
    orow[256] = (float)a2;
    orow[384] = (float)a3;
    if (has4) orow[512] = (float)a4;
}

// ====== Kernel 4: layer-1 LIF scan -> bitpacked S1 (unrolled x8) ======
__global__ void lif1(const float* __restrict__ I1, uint32_t* __restrict__ S1bits) {
#pragma clang fp contract(off)
    const int j = blockIdx.x * 256 + threadIdx.x;   // 0..1023
    float v = 0.0f;
    uint32_t word = 0;
    int t = 0;
    for (; t + 8 <= T_STEPS; t += 8) {
        float I[8];
#pragma unroll
        for (int u = 0; u < 8; ++u) I[u] = I1[(size_t)j * T_RAW + t + u];
#pragma unroll
        for (int u = 0; u < 8; ++u) {
            const int tt = t + u;
            float a = v * 0.9f;
            v = a + I[u];
            if (v >= 1.0f) { word |= (1u << (tt & 31)); v = 0.0f; }
            if ((tt & 31) == 31) { S1bits[j * 20 + (tt >> 5)] = word; word = 0; }
        }
    }
    for (; t < T_STEPS; ++t) {
        float I = I1[(size_t)j * T_RAW + t];
        float a = v * 0.9f;
        v = a + I;
        if (v >= 1.0f) { word |= (1u << (t & 31)); v = 0.0f; }
        if ((t & 31) == 31) { S1bits[j * 20 + (t >> 5)] = word; word = 0; }
    }
    S1bits[j * 20 + (T_STEPS >> 5)] = word;
}

// ====== Kernel 5: expand bits -> fp32 outputs (S0.T, S1.T) ======
__global__ void expand_out(const uint32_t* __restrict__ S0P,
                           const uint32_t* __restrict__ S1bits,
                           float* __restrict__ out) {
    const int t = blockIdx.x * 256 + threadIdx.x;
    if (t >= T_STEPS) return;
    const int row = blockIdx.y;
    if (row < N0) {
        uint32_t b = (S0P[row * S0W + 1 + (t >> 5)] >> (t & 31)) & 1u;
        out[(size_t)row * T_STEPS + t] = (float)b;
    } else {
        const int jj = row - N0;
        uint32_t b = (S1bits[jj * 20 + (t >> 5)] >> (t & 31)) & 1u;
        out[(size_t)N0 * T_STEPS + (size_t)jj * T_STEPS + t] = (float)b;
    }
}

extern "C" void kernel_launch(void* const* d_in, const int* in_sizes, int n_in,
                              void* d_out, int out_size, void* d_ws, size_t ws_size,
                              hipStream_t stream) {
    const float* stim   = (const float*)d_in[0];   // 128*128*600
    const float* W0     = (const float*)d_in[1];   // 4096*16384
    const float* W1     = (const float*)d_in[2];   // 1024*4096
    const int*   delays = (const int*)d_in[3];     // 1024*4096

    char* ws = (char*)d_ws;
    float*    I0T  = (float*)(ws + OFF_I0T);
    uint32_t* S0b  = (uint32_t*)(ws + OFF_S0B);
    float*    I1   = (float*)(ws + OFF_I1);
    uint32_t* S1b  = (uint32_t*)(ws + OFF_S1B);
    float*    out  = (float*)d_out;

    hipLaunchKernelGGL(gemm_i0_mfma, dim3(1280),   dim3(256), 0, stream, W0, stim, I0T);
    hipLaunchKernelGGL(lif0,         dim3(16),     dim3(256), 0, stream, I0T, S0b);
    hipLaunchKernelGGL(gather_i1,    dim3(1024),   dim3(128), 0, stream, W1, delays, S0b, I1);
    hipLaunchKernelGGL(lif1,         dim3(4),      dim3(256), 0, stream, I1, S1b);
    hipLaunchKernelGGL(expand_out,   dim3(3, N0 + N1), dim3(256), 0, stream, S0b, S1b, out);
}